// Round 7
// baseline (204.867 us; speedup 1.0000x reference)
//
#include <hip/hip_runtime.h>

// HMULayer omega: out[b][n] = exp(-(lam_n*||x_b-mu_n||^2 + sum_k om_nk*((x_b-mu_n).v_nk)^2)/D)
// B=1024, N=8192, D=256, K=8. 9 fused bf16 MFMA GEMMs sharing A=x.
// R11: j-split wave pairs. Unified model from R4-R10: LDS-read pipe (~8cyc/b128,
//      reads/MFMA = 1/9 + 1/rb) AND reg-count occupancy (acc144+vgpr128 = 272
//      -> 1 wave/SIMD) bind together. Fix both:
//  - wave(jh,w2): jh=0 owns j=0..4, jh=1 owns j=5..8, same 64 b-rows (rb=4).
//    acc 144->80 AGPR -> 2-3 waves/SIMD.
//  - B-tile resident in LDS (72KB one-shot stage, ZERO K-loop barriers, R10).
//  - A global->reg with 2-DEEP prefetch (1-deep was < L2 latency).
//  - Cross-half epilogue: jh=1 writes sum_k>=4 om*p^2 into scratch aliased on
//    Bs (post-loop barrier), jh=0 finishes + exp + store.
//  - LDS cap: 8w x 4.5rd x 8cyc = 320/CU/kt vs MFMA 175/SIMD/kt -> ~55% cap.

#define B_SZ 1024
#define N_SZ 8192
#define D_SZ 256
#define K_SZ 8

#define BTM 128      // main-kernel b-tile (2 row-halves x 64)
#define BT 128       // fallback b-tile
#define NT 16

typedef __bf16 bf16x8 __attribute__((ext_vector_type(8)));
typedef float f32x4 __attribute__((ext_vector_type(4)));
typedef unsigned short u16x4 __attribute__((ext_vector_type(4)));
typedef unsigned short u16x8 __attribute__((ext_vector_type(8)));

// ws byte offsets (R4 layout)
#define WS_X2   0u          // f32[1024]
#define WS_MU2  4096u       // f32[8192]
#define WS_MUV  36864u      // f32[65536]
#define WS_PX   299008u     // bf16[1024*256]   (512 KB)
#define WS_PW   823296u     // bf16[8192*9*256] (36 MB)
#define WS_NEED (823296ull + 37748736ull)

__device__ __forceinline__ float wave_reduce(float s) {
#pragma unroll
  for (int off = 32; off > 0; off >>= 1) s += __shfl_down(s, off);
  return s;
}

__device__ __forceinline__ u16x4 cvt4(float4 t) {
  u16x4 r;
  r[0] = __builtin_bit_cast(unsigned short, (__bf16)t.x);
  r[1] = __builtin_bit_cast(unsigned short, (__bf16)t.y);
  r[2] = __builtin_bit_cast(unsigned short, (__bf16)t.z);
  r[3] = __builtin_bit_cast(unsigned short, (__bf16)t.w);
  return r;
}

__device__ __forceinline__ void glds16(const void* g, const void* l) {
  __builtin_amdgcn_global_load_lds(
      (const __attribute__((address_space(1))) void*)g,
      (__attribute__((address_space(3))) void*)l, 16, 0, 0);
}

// ---- prep_all v2: one wave per row. g<1024: x-row. g<9216: mu-row. else v-row.
__global__ void prep_all(const float* __restrict__ x, const float* __restrict__ mu,
                         const float* __restrict__ v,
                         float* __restrict__ x2, unsigned short* __restrict__ px,
                         float* __restrict__ mu2, float* __restrict__ muv,
                         unsigned short* __restrict__ pw) {
  const int w = threadIdx.x >> 6, lane = threadIdx.x & 63;
  const int g = blockIdx.x * 4 + w;
  if (g < B_SZ) {
    const int b = g;
    float4 t = *(const float4*)(x + (size_t)b * D_SZ + 4 * lane);
    *(u16x4*)(px + (size_t)b * D_SZ + 4 * lane) = cvt4(t);
    float s = t.x * t.x + t.y * t.y + t.z * t.z + t.w * t.w;
    s = wave_reduce(s);
    if (lane == 0) x2[b] = s;
  } else if (g < B_SZ + N_SZ) {
    const int n = g - B_SZ;
    float4 m4 = *(const float4*)(mu + (size_t)n * D_SZ + 4 * lane);
    *(u16x4*)(pw + (size_t)n * 9 * D_SZ + 4 * lane) = cvt4(m4);
    float s = m4.x * m4.x + m4.y * m4.y + m4.z * m4.z + m4.w * m4.w;
    s = wave_reduce(s);
    if (lane == 0) mu2[n] = s;
  } else {
    const int idx = g - (B_SZ + N_SZ);
    const int n = idx >> 3, k = idx & 7;
    float4 m4 = *(const float4*)(mu + (size_t)n * D_SZ + 4 * lane);
    float4 v4 = *(const float4*)(v + ((size_t)n * K_SZ + k) * D_SZ + 4 * lane);
    *(u16x4*)(pw + ((size_t)n * 9 + k + 1) * D_SZ + 4 * lane) = cvt4(v4);
    float s = m4.x * v4.x + m4.y * v4.y + m4.z * v4.z + m4.w * v4.w;
    s = wave_reduce(s);
    if (lane == 0) muv[n * K_SZ + k] = s;
  }
}

// ---- main: j-split wave pairs, B-resident LDS, A global->reg 2-deep ----
__global__ __launch_bounds__(256, 2)
void hmu_main_p(const unsigned short* __restrict__ px,
                const unsigned short* __restrict__ pw,
                const float* __restrict__ lam, const float* __restrict__ om,
                const float* __restrict__ wsf, float* __restrict__ out) {
  // Bs: [kt(8)][j(9)*16+nl][32 elems] bf16 = 72 KB; epilogue scratch aliased.
  __shared__ __align__(16) unsigned short Bs[8 * 144 * 32];

  const float* ws_x2 = wsf;                    // WS_X2/4
  const float* ws_mu2 = wsf + 1024;            // WS_MU2/4
  const float* ws_muv = wsf + 9216;            // WS_MUV/4

  const int tid = threadIdx.x;
  const int lane = tid & 63;
  const int w = tid >> 6;        // 0..3
  const int w2 = w & 1;          // row-half: rows w2*64 .. w2*64+63
  const int jh = w >> 1;         // j-half: 0 -> j 0..4, 1 -> j 5..8
  const int m = lane & 15;
  const int kg = lane >> 4;

  // XCD-chunked decode: bid&7 = xcd; 8 b-tiles sharing a pw slice consecutive.
  const int bid = blockIdx.x;
  const int xcd = bid & 7;
  const int idx = bid >> 3;                     // 0..511 within XCD
  const int n0 = (xcd * 64 + (idx >> 3)) * NT;  // n-tile
  const int b0 = (idx & 7) * BTM;               // b-tile

  // ---- one-shot B stage: 72 slabs (kt,j), wave w stages 18.
  // LDS dest linear; global SOURCE chunk pre-swizzled (phys ch holds logical
  // ch ^ ((row>>1)&3)) so swizzled reads below are conflict-free.
  {
    const int nl4 = lane >> 2;         // row within 16
    const int ch = lane & 3;           // physical 16B chunk within 64B row
    const int kc = (ch ^ ((nl4 >> 1) & 3)) * 8;
#pragma unroll
    for (int p = 0; p < 18; ++p) {
      const int pair = w * 18 + p;     // wave-uniform
      const int kt = pair / 9, j = pair % 9;
      glds16(pw + ((size_t)(n0 + nl4) * 9 + j) * D_SZ + kt * 32 + kc,
             Bs + (kt * 144 + j * 16) * 32);
    }
  }

  // ---- A: global->reg, 2-deep prefetch (covers L2 latency > 1 kt body) ----
  const unsigned short* pxw = px + (size_t)(b0 + w2 * 64 + m) * D_SZ + kg * 8;
  bf16x8 abuf[2][4];
#pragma unroll
  for (int t = 0; t < 2; ++t)
#pragma unroll
    for (int rb = 0; rb < 4; ++rb)
      abuf[t][rb] = *(const bf16x8*)(pxw + (size_t)rb * 16 * D_SZ + t * 32);

  __syncthreads();   // drains glds16; Bs read-only until post-loop barrier

  f32x4 acc[4][5];
#pragma unroll
  for (int rb = 0; rb < 4; ++rb)
#pragma unroll
    for (int j = 0; j < 5; ++j) acc[rb][j] = (f32x4){0.f, 0.f, 0.f, 0.f};

  // read-side swizzle: logical chunk kg of row m lives at phys kg^((m>>1)&3)
  const int sw = (kg ^ ((m >> 1) & 3)) * 8;
  const int jbase = jh * 5;      // global j = jbase + j_local
  const int jn = 5 - jh;         // jh=0: 5 j's, jh=1: 4 j's (wave-uniform)

  // ---- barrier-free K-loop ----
#pragma unroll
  for (int kt = 0; kt < 8; ++kt) {
    const int sl = kt & 1;
#pragma unroll
    for (int j = 0; j < 5; ++j) {
      if (j < jn) {
        bf16x8 bfr =
            *(const bf16x8*)&Bs[(kt * 144 + (jbase + j) * 16 + m) * 32 + sw];
        acc[0][j] = __builtin_amdgcn_mfma_f32_16x16x32_bf16(abuf[sl][0], bfr, acc[0][j], 0, 0, 0);
        acc[1][j] = __builtin_amdgcn_mfma_f32_16x16x32_bf16(abuf[sl][1], bfr, acc[1][j], 0, 0, 0);
        acc[2][j] = __builtin_amdgcn_mfma_f32_16x16x32_bf16(abuf[sl][2], bfr, acc[2][j], 0, 0, 0);
        acc[3][j] = __builtin_amdgcn_mfma_f32_16x16x32_bf16(abuf[sl][3], bfr, acc[3][j], 0, 0, 0);
      }
    }
    if (kt < 6) {
#pragma unroll
      for (int rb = 0; rb < 4; ++rb)
        abuf[sl][rb] =
            *(const bf16x8*)(pxw + (size_t)rb * 16 * D_SZ + (kt + 2) * 32);
    }
  }

  // ---- epilogue: C/D layout col(n)=lane&15, row(b)=kg*4+reg ----
  const int n = n0 + m;
  __syncthreads();   // all Bs reads done -> safe to alias scratch onto Bs
  float(*sL)[17] = (float(*)[17])Bs;   // [128][17] f32 = 8.5 KB (pad: 2-way free)

  if (jh == 1) {
    // local j 0..3 = global j 5..8 = v-index k 4..7
    float omr[4], muvr[4];
#pragma unroll
    for (int k = 0; k < 4; ++k) {
      omr[k] = om[n * 8 + 4 + k];
      muvr[k] = ws_muv[n * 8 + 4 + k];
    }
#pragma unroll
    for (int rb = 0; rb < 4; ++rb)
#pragma unroll
      for (int r = 0; r < 4; ++r) {
        int row = w2 * 64 + rb * 16 + kg * 4 + r;
        float s = 0.f;
#pragma unroll
        for (int k = 0; k < 4; ++k) {
          float p = acc[rb][k][r] - muvr[k];
          s = fmaf(omr[k] * p, p, s);
        }
        sL[row][m] = s;
      }
  }
  __syncthreads();
  if (jh == 0) {
    // local j 0 = c0 (x.mu); local j 1..4 = v-index k 0..3
    const float lam_n = lam[n];
    const float mu2_n = ws_mu2[n];
    float omr[4], muvr[4];
#pragma unroll
    for (int k = 0; k < 4; ++k) {
      omr[k] = om[n * 8 + k];
      muvr[k] = ws_muv[n * 8 + k];
    }
#pragma unroll
    for (int rb = 0; rb < 4; ++rb)
#pragma unroll
      for (int r = 0; r < 4; ++r) {
        int row = w2 * 64 + rb * 16 + kg * 4 + r;
        int b = b0 + row;
        float c0 = acc[rb][0][r];
        float q = lam_n * (ws_x2[b] - 2.f * c0 + mu2_n) + sL[row][m];
#pragma unroll
        for (int k = 0; k < 4; ++k) {
          float p = acc[rb][k + 1][r] - muvr[k];
          q = fmaf(omr[k] * p, p, q);
        }
        out[(size_t)b * N_SZ + n] = __expf(q * (-1.0f / 256.0f));
      }
  }
}

// ================= fallback path (R2): in-loop cvt staging =================
__device__ __forceinline__ void cvt16_store(const float* __restrict__ src,
                                            unsigned short* dst) {
  const float4* p4 = (const float4*)src;
  float fv[16];
#pragma unroll
  for (int e = 0; e < 4; ++e) {
    float4 t = p4[e];
    fv[4 * e + 0] = t.x; fv[4 * e + 1] = t.y;
    fv[4 * e + 2] = t.z; fv[4 * e + 3] = t.w;
  }
  u16x8 lo, hi;
#pragma unroll
  for (int e = 0; e < 8; ++e) {
    lo[e] = __builtin_bit_cast(unsigned short, (__bf16)fv[e]);
    hi[e] = __builtin_bit_cast(unsigned short, (__bf16)fv[e + 8]);
  }
  *(u16x8*)dst = lo;
  *(u16x8*)(dst + 8) = hi;
}

#define LDS_STRIDE 40
__global__ __launch_bounds__(256, 2)
void hmu_main_f(const float* __restrict__ x, const float* __restrict__ mu,
                const float* __restrict__ lam, const float* __restrict__ v,
                const float* __restrict__ om, const float* __restrict__ ws,
                float* __restrict__ out) {
  __shared__ __align__(16) unsigned short As[BT * LDS_STRIDE];
  __shared__ __align__(16) unsigned short Bs[NT * 9 * LDS_STRIDE];
  const float* ws_x2 = ws;
  const float* ws_mu2 = ws + 1024;
  const float* ws_muv = ws + 9216;
  const int tid = threadIdx.x, lane = tid & 63, w = tid >> 6;
  const int m = lane & 15, kg = lane >> 4;
  const int n0 = blockIdx.x * NT, b0 = blockIdx.y * BT;
  f32x4 acc[2][9];
#pragma unroll
  for (int bs = 0; bs < 2; ++bs)
#pragma unroll
    for (int j = 0; j < 9; ++j) acc[bs][j] = (f32x4){0.f, 0.f, 0.f, 0.f};
  const int arow = tid >> 1, ahalf = tid & 1;
  for (int kt = 0; kt < 8; ++kt) {
    const int k0 = kt * 32;
    cvt16_store(x + (size_t)(b0 + arow) * D_SZ + k0 + ahalf * 16,
                &As[arow * LDS_STRIDE + ahalf * 16]);
#pragma unroll
    for (int it = 0; it < 2; ++it) {
      int idx = tid + 256 * it;
      if (idx < 288) {
        int row = idx >> 1, half = idx & 1;
        int nl = row / 9, j = row - nl * 9;
        const float* src = (j == 0)
            ? mu + (size_t)(n0 + nl) * D_SZ + k0 + half * 16
            : v + (size_t)((n0 + nl) * K_SZ + (j - 1)) * D_SZ + k0 + half * 16;
        cvt16_store(src, &Bs[row * LDS_STRIDE + half * 16]);
      }
    }
    __syncthreads();
    bf16x8 af[2];
#pragma unroll
    for (int bs = 0; bs < 2; ++bs)
      af[bs] = *(const bf16x8*)&As[((2 * w + bs) * 16 + m) * LDS_STRIDE + kg * 8];
#pragma unroll
    for (int j = 0; j < 9; ++j) {
      bf16x8 bfr = *(const bf16x8*)&Bs[(m * 9 + j) * LDS_STRIDE + kg * 8];
      acc[0][j] = __builtin_amdgcn_mfma_f32_16x16x32_bf16(af[0], bfr, acc[0][j], 0, 0, 0);
      acc[1][j] = __builtin_amdgcn_mfma_f32_16x16x32_bf16(af[1], bfr, acc[1][j], 0, 0, 0);
    }
    __syncthreads();
  }
  const int n = n0 + m;
  const float lam_n = lam[n];
  const float mu2_n = ws_mu2[n];
  float omr[8], muvr[8];
#pragma unroll
  for (int k = 0; k < 8; ++k) {
    omr[k] = om[n * 8 + k];
    muvr[k] = ws_muv[n * 8 + k];
  }
#pragma unroll
  for (int bs = 0; bs < 2; ++bs)
#pragma unroll
    for (int r = 0; r < 4; ++r) {
      int b = b0 + (2 * w + bs) * 16 + kg * 4 + r;
      float c0 = acc[bs][0][r];
      float q = lam_n * (ws_x2[b] - 2.f * c0 + mu2_n);
#pragma unroll
      for (int k = 0; k < 8; ++k) {
        float p = acc[bs][k + 1][r] - muvr[k];
        q = fmaf(omr[k] * p, p, q);
      }
      out[(size_t)b * N_SZ + n] = __expf(q * (-1.0f / 256.0f));
    }
}

__global__ void p2_mu_f(const float* __restrict__ mu, const float* __restrict__ v,
                        float* __restrict__ mu2, float* __restrict__ muv) {
  __shared__ __align__(16) float mulds[D_SZ];
  const int n = blockIdx.x;
  const int w = threadIdx.x >> 6, lane = threadIdx.x & 63;
  if (w == 0) {
    float4 m4 = *(const float4*)(mu + (size_t)n * D_SZ + 4 * lane);
    *(float4*)(mulds + 4 * lane) = m4;
    float s = m4.x * m4.x + m4.y * m4.y + m4.z * m4.z + m4.w * m4.w;
    s = wave_reduce(s);
    if (lane == 0) mu2[n] = s;
  }
  __syncthreads();
  float4 m4 = *(const float4*)(mulds + 4 * lane);
#pragma unroll
  for (int kk = 0; kk < 2; ++kk) {
    const int k = w * 2 + kk;
    float4 v4 = *(const float4*)(v + ((size_t)n * K_SZ + k) * D_SZ + 4 * lane);
    float s = m4.x * v4.x + m4.y * v4.y + m4.z * v4.z + m4.w * v4.w;
    s = wave_reduce(s);
    if (lane == 0) muv[n * K_SZ + k] = s;
  }
}

__global__ void p1_x2_f(const float* __restrict__ x, float* __restrict__ x2) {
  const int w = threadIdx.x >> 6, lane = threadIdx.x & 63;
  const int b = blockIdx.x * 4 + w;
  float4 t = *(const float4*)(x + (size_t)b * D_SZ + 4 * lane);
  float s = t.x * t.x + t.y * t.y + t.z * t.z + t.w * t.w;
  s = wave_reduce(s);
  if (lane == 0) x2[b] = s;
}

extern "C" void kernel_launch(void* const* d_in, const int* in_sizes, int n_in,
                              void* d_out, int out_size, void* d_ws, size_t ws_size,
                              hipStream_t stream) {
  const float* x   = (const float*)d_in[0];
  const float* mu  = (const float*)d_in[1];
  const float* lam = (const float*)d_in[2];
  const float* v   = (const float*)d_in[3];
  const float* om  = (const float*)d_in[4];
  float* out = (float*)d_out;
  char* wsb = (char*)d_ws;
  float* wsf = (float*)d_ws;
  float* x2  = (float*)(wsb + WS_X2);
  float* mu2 = (float*)(wsb + WS_MU2);
  float* muv = (float*)(wsb + WS_MUV);

  if (ws_size >= WS_NEED) {
    unsigned short* px = (unsigned short*)(wsb + WS_PX);
    unsigned short* pw = (unsigned short*)(wsb + WS_PW);
    const int nunits = B_SZ + N_SZ + N_SZ * K_SZ;   // 74752 waves
    prep_all<<<nunits / 4, 256, 0, stream>>>(x, mu, v, x2, px, mu2, muv, pw);
    hmu_main_p<<<(N_SZ / NT) * (B_SZ / BTM), 256, 0, stream>>>(px, pw, lam, om, wsf, out);
  } else {
    dim3 grid(N_SZ / NT, B_SZ / BT);
    p1_x2_f<<<B_SZ / 4, 256, 0, stream>>>(x, x2);
    p2_mu_f<<<N_SZ, 256, 0, stream>>>(mu, v, mu2, muv);
    hmu_main_f<<<grid, 256, 0, stream>>>(x, mu, lam, v, om, wsf, out);
  }
}

// Round 8
// 162.262 us; speedup vs baseline: 1.2626x; 1.2626x over previous
//
#include <hip/hip_runtime.h>

// HMULayer omega: out[b][n] = exp(-(lam_n*||x_b-mu_n||^2 + sum_k om_nk*((x_b-mu_n).v_nk)^2)/D)
// B=1024, N=8192, D=256, K=8. 9 fused bf16 MFMA GEMMs sharing A=x.
// R12: R9 structure EXACTLY (proven 51.4us main; R10/R11 restructures regressed)
//      + ONE variable: inner-loop register pressure.
//  - Cross-round fact: non-main time is ~111us CONSTANT (R4-R11) -> main is the
//    only lever. R9's limiter: 128 VGPR + 144 AGPR (acc[4][9]) = 272 > 256
//    -> 1 wave/SIMD (occ 17.9%); vmcnt(0) drains eat full L2 latency unhidden.
//  - Fix: software-pipeline the B-fragment reads (1 in flight + 1 in use, was
//    bfr[9]=36 regs live) and pin with sched_group_barrier {1 DS_READ, 4 MFMA}
//    so the scheduler can't re-hoist. Target VGPR<=112 -> combined<=256 ->
//    2 waves/SIMD -> 2 blocks/CU overlap.

#define B_SZ 1024
#define N_SZ 8192
#define D_SZ 256
#define K_SZ 8

#define BTM 256      // main-kernel b-tile
#define BT 128       // fallback b-tile
#define NT 16

typedef __bf16 bf16x8 __attribute__((ext_vector_type(8)));
typedef float f32x4 __attribute__((ext_vector_type(4)));
typedef unsigned short u16x4 __attribute__((ext_vector_type(4)));
typedef unsigned short u16x8 __attribute__((ext_vector_type(8)));

// ws byte offsets (R4 layout)
#define WS_X2   0u          // f32[1024]
#define WS_MU2  4096u       // f32[8192]
#define WS_MUV  36864u      // f32[65536]
#define WS_PX   299008u     // bf16[1024*256]   (512 KB)
#define WS_PW   823296u     // bf16[8192*9*256] (36 MB)
#define WS_NEED (823296ull + 37748736ull)

__device__ __forceinline__ float wave_reduce(float s) {
#pragma unroll
  for (int off = 32; off > 0; off >>= 1) s += __shfl_down(s, off);
  return s;
}

__device__ __forceinline__ u16x4 cvt4(float4 t) {
  u16x4 r;
  r[0] = __builtin_bit_cast(unsigned short, (__bf16)t.x);
  r[1] = __builtin_bit_cast(unsigned short, (__bf16)t.y);
  r[2] = __builtin_bit_cast(unsigned short, (__bf16)t.z);
  r[3] = __builtin_bit_cast(unsigned short, (__bf16)t.w);
  return r;
}

__device__ __forceinline__ void glds16(const void* g, const void* l) {
  __builtin_amdgcn_global_load_lds(
      (const __attribute__((address_space(1))) void*)g,
      (__attribute__((address_space(3))) void*)l, 16, 0, 0);
}

// ---- prep_all v2: one wave per row. g<1024: x-row. g<9216: mu-row. else v-row.
__global__ void prep_all(const float* __restrict__ x, const float* __restrict__ mu,
                         const float* __restrict__ v,
                         float* __restrict__ x2, unsigned short* __restrict__ px,
                         float* __restrict__ mu2, float* __restrict__ muv,
                         unsigned short* __restrict__ pw) {
  const int w = threadIdx.x >> 6, lane = threadIdx.x & 63;
  const int g = blockIdx.x * 4 + w;
  if (g < B_SZ) {
    const int b = g;
    float4 t = *(const float4*)(x + (size_t)b * D_SZ + 4 * lane);
    *(u16x4*)(px + (size_t)b * D_SZ + 4 * lane) = cvt4(t);
    float s = t.x * t.x + t.y * t.y + t.z * t.z + t.w * t.w;
    s = wave_reduce(s);
    if (lane == 0) x2[b] = s;
  } else if (g < B_SZ + N_SZ) {
    const int n = g - B_SZ;
    float4 m4 = *(const float4*)(mu + (size_t)n * D_SZ + 4 * lane);
    *(u16x4*)(pw + (size_t)n * 9 * D_SZ + 4 * lane) = cvt4(m4);
    float s = m4.x * m4.x + m4.y * m4.y + m4.z * m4.z + m4.w * m4.w;
    s = wave_reduce(s);
    if (lane == 0) mu2[n] = s;
  } else {
    const int idx = g - (B_SZ + N_SZ);
    const int n = idx >> 3, k = idx & 7;
    float4 m4 = *(const float4*)(mu + (size_t)n * D_SZ + 4 * lane);
    float4 v4 = *(const float4*)(v + ((size_t)n * K_SZ + k) * D_SZ + 4 * lane);
    *(u16x4*)(pw + ((size_t)n * 9 + k + 1) * D_SZ + 4 * lane) = cvt4(v4);
    float s = m4.x * v4.x + m4.y * v4.y + m4.z * v4.z + m4.w * v4.w;
    s = wave_reduce(s);
    if (lane == 0) muv[n * K_SZ + k] = s;
  }
}

// stage one K-step tile (linear LDS dest; global SOURCE chunk pre-swizzled:
// physical chunk ch holds logical chunk ch ^ ((row>>1)&3)).
__device__ __forceinline__ void stage_tile(const unsigned short* __restrict__ px,
                                           const unsigned short* __restrict__ pw,
                                           unsigned short* As, unsigned short* Bs,
                                           int b0, int n0, int k0, int w, int lane) {
  const int nl4 = lane >> 2;           // row within 16
  const int ch = lane & 3;             // physical 16B chunk within 64B row
  const int kc = (ch ^ ((nl4 >> 1) & 3)) * 8;  // logical elem offset
#pragma unroll
  for (int t = 0; t < 4; ++t) {        // A: wave w stages rows w*64 .. w*64+63
    int r0 = w * 64 + t * 16;
    glds16(px + (size_t)(b0 + r0 + nl4) * D_SZ + k0 + kc, As + r0 * 32);
  }
#pragma unroll
  for (int t = 0; t < 3; ++t) {        // B: wave w stages j = w, w+4, w+8
    int i = w + 4 * t;                 // wave-uniform guard
    if (i < 9)
      glds16(pw + ((size_t)(n0 + nl4) * 9 + i) * D_SZ + k0 + kc, Bs + i * 16 * 32);
  }
}

// ---- main: BT=256, 4 row-blocks/wave, single buffer, 2 barriers/K-step,
//      pipelined B-reads (register-pressure fix) ----
__global__ __launch_bounds__(256, 2)
void hmu_main_p(const unsigned short* __restrict__ px,
                const unsigned short* __restrict__ pw,
                const float* __restrict__ lam, const float* __restrict__ om,
                const float* __restrict__ wsf, float* __restrict__ out) {
  __shared__ __align__(16) unsigned short As[BTM * 32];      // 16 KB
  __shared__ __align__(16) unsigned short Bs[NT * 9 * 32];   // 9 KB

  const float* ws_x2 = wsf;                    // WS_X2/4
  const float* ws_mu2 = wsf + 1024;            // WS_MU2/4
  const float* ws_muv = wsf + 9216;            // WS_MUV/4

  const int tid = threadIdx.x;
  const int lane = tid & 63;
  const int w = tid >> 6;
  const int m = lane & 15;
  const int kg = lane >> 4;

  // XCD-chunked decode (R9 proven: FETCH 21MB): bid&7 = xcd, b-tile innermost.
  const int bid = blockIdx.x;
  const int xcd = bid & 7;
  const int idx = bid >> 3;                     // 0..255 within XCD
  const int n0 = (xcd * 64 + (idx >> 2)) * NT;  // n-tile
  const int b0 = (idx & 3) * BTM;               // b-tile

  f32x4 acc[4][9];
#pragma unroll
  for (int rb = 0; rb < 4; ++rb)
#pragma unroll
    for (int j = 0; j < 9; ++j) acc[rb][j] = (f32x4){0.f, 0.f, 0.f, 0.f};

  // read-side swizzle: logical chunk kg of row m lives at phys kg^((m>>1)&3)
  const int sw = (kg ^ ((m >> 1) & 3)) * 8;

  for (int kt = 0; kt < 8; ++kt) {
    stage_tile(px, pw, As, Bs, b0, n0, kt * 32, w, lane);
    __syncthreads();   // compiler emits s_waitcnt vmcnt(0) before barrier

    bf16x8 a0 = *(const bf16x8*)&As[((w * 4 + 0) * 16 + m) * 32 + sw];
    bf16x8 a1 = *(const bf16x8*)&As[((w * 4 + 1) * 16 + m) * 32 + sw];
    bf16x8 a2 = *(const bf16x8*)&As[((w * 4 + 2) * 16 + m) * 32 + sw];
    bf16x8 a3 = *(const bf16x8*)&As[((w * 4 + 3) * 16 + m) * 32 + sw];
    __builtin_amdgcn_sched_group_barrier(0x100, 4, 0);   // the 4 A ds_reads
    bf16x8 bcur = *(const bf16x8*)&Bs[(0 * 16 + m) * 32 + sw];
    __builtin_amdgcn_sched_group_barrier(0x100, 1, 0);   // B j=0 read
#pragma unroll
    for (int j = 0; j < 9; ++j) {
      bf16x8 bnxt = bcur;
      if (j < 8) bnxt = *(const bf16x8*)&Bs[((j + 1) * 16 + m) * 32 + sw];
      acc[0][j] = __builtin_amdgcn_mfma_f32_16x16x32_bf16(a0, bcur, acc[0][j], 0, 0, 0);
      acc[1][j] = __builtin_amdgcn_mfma_f32_16x16x32_bf16(a1, bcur, acc[1][j], 0, 0, 0);
      acc[2][j] = __builtin_amdgcn_mfma_f32_16x16x32_bf16(a2, bcur, acc[2][j], 0, 0, 0);
      acc[3][j] = __builtin_amdgcn_mfma_f32_16x16x32_bf16(a3, bcur, acc[3][j], 0, 0, 0);
      if (j < 8)
        __builtin_amdgcn_sched_group_barrier(0x100, 1, 0);  // next B read...
      __builtin_amdgcn_sched_group_barrier(0x8, 4, 0);      // ...then 4 MFMA
      bcur = bnxt;
    }
    __syncthreads();
  }

  // epilogue: C/D layout col(n)=lane&15, row(b)=kg*4+reg
  const int n = n0 + m;
  const float lam_n = lam[n];
  const float mu2_n = ws_mu2[n];
  float omr[8], muvr[8];
#pragma unroll
  for (int k = 0; k < 8; ++k) {
    omr[k] = om[n * 8 + k];
    muvr[k] = ws_muv[n * 8 + k];
  }
#pragma unroll
  for (int rb = 0; rb < 4; ++rb) {
#pragma unroll
    for (int r = 0; r < 4; ++r) {
      int b = b0 + (w * 4 + rb) * 16 + kg * 4 + r;
      float x2b = ws_x2[b];
      float c0 = acc[rb][0][r];
      float q = lam_n * (x2b - 2.f * c0 + mu2_n);
#pragma unroll
      for (int k = 0; k < 8; ++k) {
        float p = acc[rb][k + 1][r] - muvr[k];
        q = fmaf(omr[k] * p, p, q);
      }
      out[(size_t)b * N_SZ + n] = __expf(q * (-1.0f / 256.0f));
    }
  }
}

// ================= fallback path (R2): in-loop cvt staging =================
__device__ __forceinline__ void cvt16_store(const float* __restrict__ src,
                                            unsigned short* dst) {
  const float4* p4 = (const float4*)src;
  float fv[16];
#pragma unroll
  for (int e = 0; e < 4; ++e) {
    float4 t = p4[e];
    fv[4 * e + 0] = t.x; fv[4 * e + 1] = t.y;
    fv[4 * e + 2] = t.z; fv[4 * e + 3] = t.w;
  }
  u16x8 lo, hi;
#pragma unroll
  for (int e = 0; e < 8; ++e) {
    lo[e] = __builtin_bit_cast(unsigned short, (__bf16)fv[e]);
    hi[e] = __builtin_bit_cast(unsigned short, (__bf16)fv[e + 8]);
  }
  *(u16x8*)dst = lo;
  *(u16x8*)(dst + 8) = hi;
}

#define LDS_STRIDE 40
__global__ __launch_bounds__(256, 2)
void hmu_main_f(const float* __restrict__ x, const float* __restrict__ mu,
                const float* __restrict__ lam, const float* __restrict__ v,
                const float* __restrict__ om, const float* __restrict__ ws,
                float* __restrict__ out) {
  __shared__ __align__(16) unsigned short As[BT * LDS_STRIDE];
  __shared__ __align__(16) unsigned short Bs[NT * 9 * LDS_STRIDE];
  const float* ws_x2 = ws;
  const float* ws_mu2 = ws + 1024;
  const float* ws_muv = ws + 9216;
  const int tid = threadIdx.x, lane = tid & 63, w = tid >> 6;
  const int m = lane & 15, kg = lane >> 4;
  const int n0 = blockIdx.x * NT, b0 = blockIdx.y * BT;
  f32x4 acc[2][9];
#pragma unroll
  for (int bs = 0; bs < 2; ++bs)
#pragma unroll
    for (int j = 0; j < 9; ++j) acc[bs][j] = (f32x4){0.f, 0.f, 0.f, 0.f};
  const int arow = tid >> 1, ahalf = tid & 1;
  for (int kt = 0; kt < 8; ++kt) {
    const int k0 = kt * 32;
    cvt16_store(x + (size_t)(b0 + arow) * D_SZ + k0 + ahalf * 16,
                &As[arow * LDS_STRIDE + ahalf * 16]);
#pragma unroll
    for (int it = 0; it < 2; ++it) {
      int idx = tid + 256 * it;
      if (idx < 288) {
        int row = idx >> 1, half = idx & 1;
        int nl = row / 9, j = row - nl * 9;
        const float* src = (j == 0)
            ? mu + (size_t)(n0 + nl) * D_SZ + k0 + half * 16
            : v + (size_t)((n0 + nl) * K_SZ + (j - 1)) * D_SZ + k0 + half * 16;
        cvt16_store(src, &Bs[row * LDS_STRIDE + half * 16]);
      }
    }
    __syncthreads();
    bf16x8 af[2];
#pragma unroll
    for (int bs = 0; bs < 2; ++bs)
      af[bs] = *(const bf16x8*)&As[((2 * w + bs) * 16 + m) * LDS_STRIDE + kg * 8];
#pragma unroll
    for (int j = 0; j < 9; ++j) {
      bf16x8 bfr = *(const bf16x8*)&Bs[(m * 9 + j) * LDS_STRIDE + kg * 8];
      acc[0][j] = __builtin_amdgcn_mfma_f32_16x16x32_bf16(af[0], bfr, acc[0][j], 0, 0, 0);
      acc[1][j] = __builtin_amdgcn_mfma_f32_16x16x32_bf16(af[1], bfr, acc[1][j], 0, 0, 0);
    }
    __syncthreads();
  }
  const int n = n0 + m;
  const float lam_n = lam[n];
  const float mu2_n = ws_mu2[n];
  float omr[8], muvr[8];
#pragma unroll
  for (int k = 0; k < 8; ++k) {
    omr[k] = om[n * 8 + k];
    muvr[k] = ws_muv[n * 8 + k];
  }
#pragma unroll
  for (int bs = 0; bs < 2; ++bs)
#pragma unroll
    for (int r = 0; r < 4; ++r) {
      int b = b0 + (2 * w + bs) * 16 + kg * 4 + r;
      float c0 = acc[bs][0][r];
      float q = lam_n * (ws_x2[b] - 2.f * c0 + mu2_n);
#pragma unroll
      for (int k = 0; k < 8; ++k) {
        float p = acc[bs][k + 1][r] - muvr[k];
        q = fmaf(omr[k] * p, p, q);
      }
      out[(size_t)b * N_SZ + n] = __expf(q * (-1.0f / 256.0f));
    }
}

__global__ void p2_mu_f(const float* __restrict__ mu, const float* __restrict__ v,
                        float* __restrict__ mu2, float* __restrict__ muv) {
  __shared__ __align__(16) float mulds[D_SZ];
  const int n = blockIdx.x;
  const int w = threadIdx.x >> 6, lane = threadIdx.x & 63;
  if (w == 0) {
    float4 m4 = *(const float4*)(mu + (size_t)n * D_SZ + 4 * lane);
    *(float4*)(mulds + 4 * lane) = m4;
    float s = m4.x * m4.x + m4.y * m4.y + m4.z * m4.z + m4.w * m4.w;
    s = wave_reduce(s);
    if (lane == 0) mu2[n] = s;
  }
  __syncthreads();
  float4 m4 = *(const float4*)(mulds + 4 * lane);
#pragma unroll
  for (int kk = 0; kk < 2; ++kk) {
    const int k = w * 2 + kk;
    float4 v4 = *(const float4*)(v + ((size_t)n * K_SZ + k) * D_SZ + 4 * lane);
    float s = m4.x * v4.x + m4.y * v4.y + m4.z * v4.z + m4.w * v4.w;
    s = wave_reduce(s);
    if (lane == 0) muv[n * K_SZ + k] = s;
  }
}

__global__ void p1_x2_f(const float* __restrict__ x, float* __restrict__ x2) {
  const int w = threadIdx.x >> 6, lane = threadIdx.x & 63;
  const int b = blockIdx.x * 4 + w;
  float4 t = *(const float4*)(x + (size_t)b * D_SZ + 4 * lane);
  float s = t.x * t.x + t.y * t.y + t.z * t.z + t.w * t.w;
  s = wave_reduce(s);
  if (lane == 0) x2[b] = s;
}

extern "C" void kernel_launch(void* const* d_in, const int* in_sizes, int n_in,
                              void* d_out, int out_size, void* d_ws, size_t ws_size,
                              hipStream_t stream) {
  const float* x   = (const float*)d_in[0];
  const float* mu  = (const float*)d_in[1];
  const float* lam = (const float*)d_in[2];
  const float* v   = (const float*)d_in[3];
  const float* om  = (const float*)d_in[4];
  float* out = (float*)d_out;
  char* wsb = (char*)d_ws;
  float* wsf = (float*)d_ws;
  float* x2  = (float*)(wsb + WS_X2);
  float* mu2 = (float*)(wsb + WS_MU2);
  float* muv = (float*)(wsb + WS_MUV);

  if (ws_size >= WS_NEED) {
    unsigned short* px = (unsigned short*)(wsb + WS_PX);
    unsigned short* pw = (unsigned short*)(wsb + WS_PW);
    const int nunits = B_SZ + N_SZ + N_SZ * K_SZ;   // 74752 waves
    prep_all<<<nunits / 4, 256, 0, stream>>>(x, mu, v, x2, px, mu2, muv, pw);
    hmu_main_p<<<(N_SZ / NT) * (B_SZ / BTM), 256, 0, stream>>>(px, pw, lam, om, wsf, out);
  } else {
    dim3 grid(N_SZ / NT, B_SZ / BT);
    p1_x2_f<<<B_SZ / 4, 256, 0, stream>>>(x, x2);
    p2_mu_f<<<N_SZ, 256, 0, stream>>>(mu, v, mu2, muv);
    hmu_main_f<<<grid, 256, 0, stream>>>(x, mu, lam, v, om, wsf, out);
  }
}